// Round 17
// baseline (778.322 us; speedup 1.0000x reference)
//
#include <hip/hip_runtime.h>
#include <hip/hip_bf16.h>
#include <cstddef>

// Problem constants
#define BATCH 32
#define TSTEPS 20
#define IN_DIM 3
#define WIDTH 256
#define HID 64
#define FC1_IN 327680   // HID * TSTEPS * WIDTH
#define FC1_OUT 512
#define OUT_DIM 3

// Conv time-chunking geometry
#define CST 5     // steps per chunk (4 chunks)
#define MARG 6    // halo margin >= CST+1
#define REGC 44   // region cols computed per block
#define CORE 6    // core starts at n=CORE
#define ROWS 50   // LDS slab rows
#define CROWS 48  // c-state rows

// FC1 K-split (r12-proven geometry; B operand now fp16 from w1h)
#define KSLICE 1280
#define KPHASE 640
#define NSPLIT 256

// w1 -> fp16 conversion, fused into conv phases.
// Total float4s in w1: 512*327680/4 = 41,943,040. Region per (phase,block):
// L0: 4 waves x 2 batches x 12 f4 x 64 lanes = 6144; L1: 4x2x2x64 = 1024;
// 7168 f4/block/phase x 256 blocks x 24 global phases = 44,040,192 >= NF4.
#define NF4 41943040ULL
#define BLKF4 7168

typedef _Float16 half8 __attribute__((ext_vector_type(8)));
typedef _Float16 half4 __attribute__((ext_vector_type(4)));
typedef float floatx4 __attribute__((ext_vector_type(4)));

__device__ __forceinline__ float sigm(float x) {
    return 1.0f / (1.0f + __expf(-x));
}
__device__ __forceinline__ float tanh_fast(float x) {
    return 1.0f - 2.0f / (__expf(2.0f * x) + 1.0f);
}

// ---------------- prep kernels (once per launch) ----------------

// wt0[kw][co][cip=96]: cip 0..63 = h ch (orig ci 3+cip), 64..66 = x ch, 67..95 = 0.
__global__ __launch_bounds__(256) void prep_w0(
    const float* __restrict__ cw0, _Float16* __restrict__ wt0)
{
    int e = blockIdx.x * 256 + threadIdx.x;   // < 256*96
    if (e >= 256 * 96) return;
    int co = e / 96, cip = e - co * 96;
    int ci = (cip < 64) ? (3 + cip) : (cip < 67 ? cip - 64 : -1);
    float v[3] = {0.f, 0.f, 0.f};
    if (ci >= 0) {
#pragma unroll
        for (int kw = 0; kw < 3; ++kw)
            v[kw] = cw0[(size_t)(co * 67 + ci) * 9 + 3 + kw];
    }
#pragma unroll
    for (int kw = 0; kw < 3; ++kw)
        wt0[(size_t)(kw * 256 + co) * 96 + cip] = (_Float16)v[kw];
}

// wt1[kw][co][ci=128]: direct (z = [h0 64 | h1 64] matches cw1 ci order).
__global__ __launch_bounds__(256) void prep_w1(
    const float* __restrict__ cw1, _Float16* __restrict__ wt1)
{
    int e = blockIdx.x * 256 + threadIdx.x;   // < 256*128
    int co = e >> 7, ci = e & 127;
#pragma unroll
    for (int kw = 0; kw < 3; ++kw)
        wt1[(size_t)(kw * 256 + co) * 128 + ci] =
            (_Float16)cw1[(size_t)(co * 128 + ci) * 9 + 3 + kw];
}

// xT[t][b][w][8] fp16: ch 0..2 from x[b][t][ch][w], 3..7 = 0.
__global__ __launch_bounds__(256) void prep_x(
    const float* __restrict__ x, _Float16* __restrict__ xT)
{
    int e = blockIdx.x * 256 + threadIdx.x;   // < 20*32*256
    if (e >= TSTEPS * BATCH * WIDTH) return;
    int t = e / (BATCH * WIDTH);
    int rem = e - t * BATCH * WIDTH;
    int b = rem >> 8, w = rem & 255;
    half8 v = {};
#pragma unroll
    for (int ci = 0; ci < 3; ++ci)
        v[ci] = (_Float16)x[(size_t)((b * TSTEPS + t) * IN_DIM + ci) * WIDTH + w];
    *(half8*)&xT[(size_t)e * 8] = v;
}

// ---------------- time-chunked ConvLSTM kernel (5 steps/launch) ----------
// Conv math identical to round-11/12 (431.8us-best). Added: fused w1->fp16
// conversion riding the idle HBM during conv (issue-early/consume-late
// batches; L0 waves 12 float4/batch, L1 waves 2; one reused buffer so live
// ranges chain; stores are fire-and-forget; kernel boundary makes w1h
// visible to fc1).
__global__ __launch_bounds__(512) void conv_chunk(
    const _Float16* __restrict__ xT,   // [t][b][w][8]
    const _Float16* __restrict__ wt0,  // [3][256][96]  (reordered slots)
    const _Float16* __restrict__ wt1,  // [3][256][128]
    const float* __restrict__ cb0,
    const float* __restrict__ cb1,
    _Float16* __restrict__ fcin,       // [b][(t*64+hc)*256+w] fp16
    _Float16* __restrict__ h0g,        // [b][w][64] state between chunks
    _Float16* __restrict__ h1g,
    float* __restrict__ c0g,
    float* __restrict__ c1g,
    const float* __restrict__ w1,      // fc1_w fp32 (conversion source)
    _Float16* __restrict__ w1h,        // fc1_w fp16 (conversion dest)
    int t0, int first, int save)
{
    __shared__ __align__(16) _Float16 h0s[2][ROWS * 64];
    __shared__ __align__(16) _Float16 h1s[2][ROWS * 64];
    __shared__ __align__(16) _Float16 xs[2][ROWS * 8];
    __shared__ float c0s[CROWS * 64];   // idx n*64 + (hc ^ (owner_kg<<4))
    __shared__ float c1s[CROWS * 64];
    __shared__ __align__(16) _Float16 zero16[8];

    const int b    = blockIdx.x;
    const int w0   = blockIdx.y * 32;
    const int bid  = blockIdx.y * 32 + blockIdx.x;   // 0..255
    const int kk   = t0 / CST;                       // launch index 0..3
    const int tid  = threadIdx.x;
    const int wave = tid >> 6;
    const int ln = tid & 63;
    const int lr = ln & 15;
    const int kg = ln >> 4;
    const float4* w1v = (const float4*)w1;

    // ---- zero-init LDS
    {
        _Float16* h0f = &h0s[0][0];
        _Float16* h1f = &h1s[0][0];
        for (int i = tid; i < 2 * ROWS * 64; i += 512) { h0f[i] = (_Float16)0.0f; h1f[i] = (_Float16)0.0f; }
        for (int i = tid; i < CROWS * 64; i += 512) { c0s[i] = 0.0f; c1s[i] = 0.0f; }
        for (int i = tid; i < ROWS * 8; i += 512) xs[1][i] = (_Float16)0.0f;
        if (tid < 8) zero16[tid] = (_Float16)0.0f;
    }
    __syncthreads();

    // ---- stage x(t0) + load chunk-start state
    {
        if (tid < ROWS) {
            int w = w0 - 7 + tid;
            half8 v = {};
            if (w >= 0 && w < WIDTH)
                v = *(const half8*)&xT[((size_t)(t0 * BATCH + b) * WIDTH + w) * 8];
            *(half8*)&xs[0][tid * 8] = v;
        }
        if (!first) {
            for (int i = tid; i < REGC * 8; i += 512) {
                int row = 1 + (i >> 3), c = i & 7;
                int w = w0 - 7 + row;
                half8 v0 = {}, v1 = {};
                if (w >= 0 && w < WIDTH) {
                    v0 = *(const half8*)&h0g[((size_t)b * WIDTH + w) * 64 + c * 8];
                    v1 = *(const half8*)&h1g[((size_t)b * WIDTH + w) * 64 + c * 8];
                }
                int phys = c ^ (row & 7);
                *(half8*)&h0s[1][row * 64 + phys * 8] = v0;
                *(half8*)&h1s[1][row * 64 + phys * 8] = v1;
            }
            for (int i = tid; i < REGC * 64; i += 512) {
                int n = i >> 6, hc = i & 63;
                int w = w0 - 6 + n;
                float v0 = 0.f, v1 = 0.f;
                if (w >= 0 && w < WIDTH) {
                    v0 = c0g[((size_t)b * WIDTH + w) * 64 + hc];
                    v1 = c1g[((size_t)b * WIDTH + w) * 64 + hc];
                }
                int ci = n * 64 + (hc ^ (((n >> 2) & 3) << 4));
                c0s[ci] = v0;
                c1s[ci] = v1;
            }
        }
    }

    if (wave < 4) {
        // ================= LAYER-0 WAVES =================
        const int hc = wave * 16 + lr;

        half8 b0r[3][3][4];
#pragma unroll
        for (int kw = 0; kw < 3; ++kw)
#pragma unroll
        for (int kf = 0; kf < 3; ++kf)
#pragma unroll
        for (int cf = 0; cf < 4; ++cf)
            b0r[kw][kf][cf] = *(const half8*)&wt0[
                (size_t)(kw * 256 + cf * 64 + hc) * 96 + kf * 32 + kg * 8];

        float cbr0[4];
#pragma unroll
        for (int cf = 0; cf < 4; ++cf) cbr0[cf] = cb0[cf * 64 + hc];

        float4 cbuf[12];
        size_t hbase = 0;

        __syncthreads();   // init barrier

        for (int p = 0; p <= CST; ++p) {
            const int rd = (p ^ 1) & 1;
            const int wr = p & 1;
            const size_t rbase = ((size_t)(kk * 6 + p) * 256 + bid) * BLKF4;

            // consume batch B held from previous phase
            if (p > 0) {
#pragma unroll
                for (int i = 0; i < 12; ++i) {
                    size_t idx = hbase + (size_t)i * 64 + ln;
                    if (idx < NF4) {
                        half4 hv4;
                        hv4[0] = (_Float16)cbuf[i].x; hv4[1] = (_Float16)cbuf[i].y;
                        hv4[2] = (_Float16)cbuf[i].z; hv4[3] = (_Float16)cbuf[i].w;
                        *(half4*)&w1h[idx * 4] = hv4;
                    }
                }
            }
            // issue batch A (consumed after the MFMA block)
            const size_t abase = rbase + (size_t)(wave * 2 + 0) * 768;
#pragma unroll
            for (int i = 0; i < 12; ++i) {
                size_t idx = abase + (size_t)i * 64 + ln;
                cbuf[i] = (idx < NF4) ? w1v[idx] : float4{0.f, 0.f, 0.f, 0.f};
            }

            half8 xreg = {};
            const bool xst = (p < CST - 1) && (tid < ROWS);
            if (xst) {
                int w = w0 - 7 + tid;
                if (w >= 0 && w < WIDTH)
                    xreg = *(const half8*)&xT[((size_t)((t0 + p + 1) * BATCH + b) * WIDTH + w) * 8];
            }
            if (p < CST) {
#pragma unroll
                for (int j = 0; j < 3; ++j) {
                    floatx4 acc[4];
#pragma unroll
                    for (int cf = 0; cf < 4; ++cf) acc[cf] = (floatx4)0.0f;
                    __builtin_amdgcn_s_setprio(1);
#pragma unroll
                    for (int kw = 0; kw < 3; ++kw)
#pragma unroll
                    for (int kf = 0; kf < 3; ++kf) {
                        int row = 16 * j + lr + kw;
                        half8 a;
                        if (kf < 2) {
                            int phys = (kf * 4 + kg) ^ (row & 7);
                            a = *(const half8*)&h0s[rd][row * 64 + phys * 8];
                        } else {
                            a = (kg == 0) ? *(const half8*)&xs[wr][row * 8]
                                          : *(const half8*)&zero16[0];
                        }
#pragma unroll
                        for (int cf = 0; cf < 4; ++cf)
                            acc[cf] = __builtin_amdgcn_mfma_f32_16x16x32_f16(a, b0r[kw][kf][cf], acc[cf], 0, 0, 0);
                    }
                    __builtin_amdgcn_s_setprio(0);
#pragma unroll
                    for (int r = 0; r < 4; ++r) {
                        int n = 16 * j + kg * 4 + r;
                        int cidx = n * 64 + (hc ^ (kg << 4));
                        float cv = c0s[cidx];
                        float cn = sigm(acc[1][r] + cbr0[1]) * cv
                                 + sigm(acc[0][r] + cbr0[0]) * tanh_fast(acc[3][r] + cbr0[3]);
                        c0s[cidx] = cn;
                        int w = w0 - 6 + n;
                        if (w >= 0 && w < WIDTH) {
                            _Float16 hv = (_Float16)(sigm(acc[2][r] + cbr0[2]) * tanh_fast(cn));
                            int rowo = n + 1;
                            int phys = (hc >> 3) ^ (rowo & 7);
                            *((_Float16*)((char*)&h0s[wr][0] + rowo * 128 + phys * 16 + (hc & 7) * 2)) = hv;
                        }
                    }
                }
            }
            // consume batch A
#pragma unroll
            for (int i = 0; i < 12; ++i) {
                size_t idx = abase + (size_t)i * 64 + ln;
                if (idx < NF4) {
                    half4 hv4;
                    hv4[0] = (_Float16)cbuf[i].x; hv4[1] = (_Float16)cbuf[i].y;
                    hv4[2] = (_Float16)cbuf[i].z; hv4[3] = (_Float16)cbuf[i].w;
                    *(half4*)&w1h[idx * 4] = hv4;
                }
            }
            // issue batch B (held across the barrier)
            hbase = rbase + (size_t)(wave * 2 + 1) * 768;
#pragma unroll
            for (int i = 0; i < 12; ++i) {
                size_t idx = hbase + (size_t)i * 64 + ln;
                cbuf[i] = (idx < NF4) ? w1v[idx] : float4{0.f, 0.f, 0.f, 0.f};
            }
            if (xst) *(half8*)&xs[(p + 1) & 1][tid * 8] = xreg;
            __syncthreads();
        }
        // tail: consume final batch B
#pragma unroll
        for (int i = 0; i < 12; ++i) {
            size_t idx = hbase + (size_t)i * 64 + ln;
            if (idx < NF4) {
                half4 hv4;
                hv4[0] = (_Float16)cbuf[i].x; hv4[1] = (_Float16)cbuf[i].y;
                hv4[2] = (_Float16)cbuf[i].z; hv4[3] = (_Float16)cbuf[i].w;
                *(half4*)&w1h[idx * 4] = hv4;
            }
        }
    } else {
        // ================= LAYER-1 WAVES =================
        const int hc = (wave - 4) * 16 + lr;

        half8 b1r[3][4][4];
#pragma unroll
        for (int kw = 0; kw < 3; ++kw)
#pragma unroll
        for (int kf = 0; kf < 4; ++kf)
#pragma unroll
        for (int cf = 0; cf < 4; ++cf)
            b1r[kw][kf][cf] = *(const half8*)&wt1[
                (size_t)(kw * 256 + cf * 64 + hc) * 128 + kf * 32 + kg * 8];

        float cbr1[4];
#pragma unroll
        for (int cf = 0; cf < 4; ++cf) cbr1[cf] = cb1[cf * 64 + hc];

        float4 dbuf[2];
        size_t hbase = 0;

        __syncthreads();   // init barrier

        for (int p = 0; p <= CST; ++p) {
            const int rd   = (p ^ 1) & 1;
            const int h1rd = p & 1;
            const size_t rbase = ((size_t)(kk * 6 + p) * 256 + bid) * BLKF4;

            if (p > 0) {
#pragma unroll
                for (int i = 0; i < 2; ++i) {
                    size_t idx = hbase + (size_t)i * 64 + ln;
                    if (idx < NF4) {
                        half4 hv4;
                        hv4[0] = (_Float16)dbuf[i].x; hv4[1] = (_Float16)dbuf[i].y;
                        hv4[2] = (_Float16)dbuf[i].z; hv4[3] = (_Float16)dbuf[i].w;
                        *(half4*)&w1h[idx * 4] = hv4;
                    }
                }
            }
            const size_t abase = rbase + 6144 + (size_t)((wave - 4) * 2 + 0) * 128;
#pragma unroll
            for (int i = 0; i < 2; ++i) {
                size_t idx = abase + (size_t)i * 64 + ln;
                dbuf[i] = (idx < NF4) ? w1v[idx] : float4{0.f, 0.f, 0.f, 0.f};
            }

            if (p >= 1) {
#pragma unroll
                for (int j = 0; j < 3; ++j) {
                    floatx4 acc[4];
#pragma unroll
                    for (int cf = 0; cf < 4; ++cf) acc[cf] = (floatx4)0.0f;
                    __builtin_amdgcn_s_setprio(1);
#pragma unroll
                    for (int kw = 0; kw < 3; ++kw)
#pragma unroll
                    for (int kf = 0; kf < 4; ++kf) {
                        int row = 16 * j + lr + kw;
                        half8 a;
                        if (kf < 2) {
                            int phys = (kf * 4 + kg) ^ (row & 7);
                            a = *(const half8*)&h0s[rd][row * 64 + phys * 8];
                        } else {
                            int phys = ((kf - 2) * 4 + kg) ^ (row & 7);
                            a = *(const half8*)&h1s[h1rd][row * 64 + phys * 8];
                        }
#pragma unroll
                        for (int cf = 0; cf < 4; ++cf)
                            acc[cf] = __builtin_amdgcn_mfma_f32_16x16x32_f16(a, b1r[kw][kf][cf], acc[cf], 0, 0, 0);
                    }
                    __builtin_amdgcn_s_setprio(0);
#pragma unroll
                    for (int r = 0; r < 4; ++r) {
                        int n = 16 * j + kg * 4 + r;
                        int cidx = n * 64 + (hc ^ (kg << 4));
                        float cv = c1s[cidx];
                        float cn = sigm(acc[1][r] + cbr1[1]) * cv
                                 + sigm(acc[0][r] + cbr1[0]) * tanh_fast(acc[3][r] + cbr1[3]);
                        c1s[cidx] = cn;
                        _Float16 hv = (_Float16)(sigm(acc[2][r] + cbr1[2]) * tanh_fast(cn));
                        int w = w0 - 6 + n;
                        if (w >= 0 && w < WIDTH) {
                            int rowo = n + 1;
                            int phys = (hc >> 3) ^ (rowo & 7);
                            *((_Float16*)((char*)&h1s[rd][0] + rowo * 128 + phys * 16 + (hc & 7) * 2)) = hv;
                        }
                        if (n >= CORE && n < CORE + 32)
                            fcin[(size_t)b * FC1_IN + (size_t)((t0 + p - 1) * HID + hc) * WIDTH + w] = hv;
                    }
                }
            }
#pragma unroll
            for (int i = 0; i < 2; ++i) {
                size_t idx = abase + (size_t)i * 64 + ln;
                if (idx < NF4) {
                    half4 hv4;
                    hv4[0] = (_Float16)dbuf[i].x; hv4[1] = (_Float16)dbuf[i].y;
                    hv4[2] = (_Float16)dbuf[i].z; hv4[3] = (_Float16)dbuf[i].w;
                    *(half4*)&w1h[idx * 4] = hv4;
                }
            }
            hbase = rbase + 6144 + (size_t)((wave - 4) * 2 + 1) * 128;
#pragma unroll
            for (int i = 0; i < 2; ++i) {
                size_t idx = hbase + (size_t)i * 64 + ln;
                dbuf[i] = (idx < NF4) ? w1v[idx] : float4{0.f, 0.f, 0.f, 0.f};
            }
            __syncthreads();
        }
#pragma unroll
        for (int i = 0; i < 2; ++i) {
            size_t idx = hbase + (size_t)i * 64 + ln;
            if (idx < NF4) {
                half4 hv4;
                hv4[0] = (_Float16)dbuf[i].x; hv4[1] = (_Float16)dbuf[i].y;
                hv4[2] = (_Float16)dbuf[i].z; hv4[3] = (_Float16)dbuf[i].w;
                *(half4*)&w1h[idx * 4] = hv4;
            }
        }
    }

    // ---- store core state for next chunk (h0/h1 final in buffer 0)
    if (save) {
        for (int i = tid; i < 32 * 64; i += 512) {
            int n = CORE + (i >> 6);
            int hc = i & 63;
            int w = w0 + (i >> 6);
            int rowo = n + 1;
            int physh = (hc >> 3) ^ (rowo & 7);
            h0g[((size_t)b * WIDTH + w) * 64 + hc] = h0s[0][rowo * 64 + physh * 8 + (hc & 7)];
            h1g[((size_t)b * WIDTH + w) * 64 + hc] = h1s[0][rowo * 64 + physh * 8 + (hc & 7)];
            int ci = n * 64 + (hc ^ (((n >> 2) & 3) << 4));
            c0g[((size_t)b * WIDTH + w) * 64 + hc] = c0s[ci];
            c1g[((size_t)b * WIDTH + w) * 64 + hc] = c1s[ci];
        }
    }
}

// ---------------- FC1 fp16 MFMA GEMM, K-split (fp16 B from w1h) ----------
__global__ __launch_bounds__(512) void fc1_mfma(
    const _Float16* __restrict__ a,   // fcin [32][327680] fp16
    const _Float16* __restrict__ wh,  // w1h [512][327680] fp16
    float* __restrict__ part)         // [256][512][32] fp32 partials
{
    __shared__ _Float16 alds[32 * 648];

    const int blk = blockIdx.x;
    const int tid = threadIdx.x;
    const int wv  = tid >> 6;
    const int ln  = tid & 63;
    const int lg  = ln >> 4;
    const int lr  = ln & 15;
    const int k0  = blk * KSLICE;

    floatx4 acc[2][4];
#pragma unroll
    for (int bt = 0; bt < 2; ++bt)
#pragma unroll
        for (int nt = 0; nt < 4; ++nt) acc[bt][nt] = (floatx4)0.0f;

    const _Float16* wbase[4];
#pragma unroll
    for (int nt = 0; nt < 4; ++nt)
        wbase[nt] = wh + (size_t)(wv * 64 + nt * 16 + lr) * FC1_IN + k0 + lg * 8;

    for (int p = 0; p < 2; ++p) {
        __syncthreads();
        for (int i = tid; i < 32 * 80; i += 512) {
            int r = i / 80;
            int c = (i - r * 80) * 8;
            *(half8*)&alds[r * 648 + c] =
                *(const half8*)&a[(size_t)r * FC1_IN + k0 + p * KPHASE + c];
        }
        __syncthreads();

        for (int kc = 0; kc < KPHASE / 32; ++kc) {
            half8 af0 = *(const half8*)&alds[lr * 648 + kc * 32 + lg * 8];
            half8 af1 = *(const half8*)&alds[(16 + lr) * 648 + kc * 32 + lg * 8];
#pragma unroll
            for (int nt = 0; nt < 4; ++nt) {
                half8 bf = *(const half8*)(wbase[nt] + p * KPHASE + kc * 32);
                acc[0][nt] = __builtin_amdgcn_mfma_f32_16x16x32_f16(af0, bf, acc[0][nt], 0, 0, 0);
                acc[1][nt] = __builtin_amdgcn_mfma_f32_16x16x32_f16(af1, bf, acc[1][nt], 0, 0, 0);
            }
        }
    }

#pragma unroll
    for (int bt = 0; bt < 2; ++bt)
#pragma unroll
        for (int nt = 0; nt < 4; ++nt) {
            int n = wv * 64 + nt * 16 + lr;
            int b = bt * 16 + lg * 4;
            *(float4*)&part[((size_t)blk * FC1_OUT + n) * BATCH + b] =
                *(float4*)&acc[bt][nt];
        }
}

__global__ __launch_bounds__(256) void fc1_reduce(
    const float* __restrict__ part, const float* __restrict__ b1,
    float* __restrict__ z1)
{
    int e = blockIdx.x * 256 + threadIdx.x;  // e = n*32 + b
    float s = 0.0f;
    for (int ks = 0; ks < NSPLIT; ++ks)
        s += part[(size_t)ks * (FC1_OUT * BATCH) + e];
    int n = e >> 5, b = e & 31;
    float v = s + b1[n];
    z1[(size_t)b * FC1_OUT + n] = v > 0.0f ? v : 0.0f;
}

__global__ __launch_bounds__(128) void fc2_kernel(
    const float* __restrict__ z1, const float* __restrict__ w2,
    const float* __restrict__ b2, float* __restrict__ out)
{
    int t = threadIdx.x;
    if (t >= BATCH * OUT_DIM) return;
    int b = t / OUT_DIM, n = t - b * OUT_DIM;
    const float* zr = z1 + (size_t)b * FC1_OUT;
    const float* wr = w2 + (size_t)n * FC1_OUT;
    float acc = b2[n];
    for (int k = 0; k < FC1_OUT; ++k) acc += zr[k] * wr[k];
    if (n == 2) acc = sigm(acc);
    out[(size_t)b * OUT_DIM + n] = acc;
}

extern "C" void kernel_launch(void* const* d_in, const int* in_sizes, int n_in,
                              void* d_out, int out_size, void* d_ws, size_t ws_size,
                              hipStream_t stream) {
    const float* x   = (const float*)d_in[0];
    const float* cw0 = (const float*)d_in[1];
    const float* cb0 = (const float*)d_in[2];
    const float* cw1 = (const float*)d_in[3];
    const float* cb1 = (const float*)d_in[4];
    const float* w1  = (const float*)d_in[5];
    const float* b1  = (const float*)d_in[6];
    const float* w2  = (const float*)d_in[7];
    const float* b2  = (const float*)d_in[8];
    float* out = (float*)d_out;

    const size_t S = (size_t)BATCH * WIDTH * HID;   // 524288 elements
    char* p = (char*)d_ws;
    auto alloc = [&](size_t bytes) { char* r = p; p += (bytes + 255) & ~(size_t)255; return r; };

    _Float16* wt0  = (_Float16*)alloc((size_t)3 * 256 * 96 * 2);
    _Float16* wt1  = (_Float16*)alloc((size_t)3 * 256 * 128 * 2);
    _Float16* xT   = (_Float16*)alloc((size_t)TSTEPS * BATCH * WIDTH * 8 * 2);
    _Float16* fcin = (_Float16*)alloc((size_t)BATCH * FC1_IN * 2);
    _Float16* h0g  = (_Float16*)alloc(S * 2);
    _Float16* h1g  = (_Float16*)alloc(S * 2);
    float*    c0g  = (float*)alloc(S * 4);
    float*    c1g  = (float*)alloc(S * 4);
    float*    part = (float*)alloc((size_t)NSPLIT * FC1_OUT * BATCH * 4);
    float*    z1   = (float*)alloc((size_t)BATCH * FC1_OUT * 4);
    _Float16* w1h  = (_Float16*)alloc((size_t)FC1_OUT * FC1_IN * 2);  // 336 MB

    prep_w0<<<96, 256, 0, stream>>>(cw0, wt0);
    prep_w1<<<128, 256, 0, stream>>>(cw1, wt1);
    prep_x<<<(TSTEPS * BATCH * WIDTH + 255) / 256, 256, 0, stream>>>(x, xT);

    for (int k = 0; k < 4; ++k) {
        conv_chunk<<<dim3(BATCH, 8), 512, 0, stream>>>(
            xT, wt0, wt1, cb0, cb1, fcin, h0g, h1g, c0g, c1g,
            w1, w1h,
            k * CST, (k == 0) ? 1 : 0, (k < 3) ? 1 : 0);
    }

    fc1_mfma<<<NSPLIT, 512, 0, stream>>>(fcin, w1h, part);
    fc1_reduce<<<64, 256, 0, stream>>>(part, b1, z1);
    fc2_kernel<<<1, 128, 0, stream>>>(z1, w2, b2, out);
}

// Round 18
// 398.627 us; speedup vs baseline: 1.9525x; 1.9525x over previous
//
#include <hip/hip_runtime.h>
#include <hip/hip_bf16.h>
#include <cstddef>

// Problem constants
#define BATCH 32
#define TSTEPS 20
#define IN_DIM 3
#define WIDTH 256
#define HID 64
#define FC1_IN 327680   // HID * TSTEPS * WIDTH
#define FC1_OUT 512
#define OUT_DIM 3

// Conv time-chunking geometry: 3 chunks of (7,7,6) steps.
// MARG=8 >= 7+1; REGC=48 = exactly 3 j-tiles of 16 (zero junk rows).
#define MARG 8    // halo margin
#define REGC 48   // region cols computed per block (32 core + 2*MARG)
#define CORE 8    // core starts at n=CORE
#define ROWS 50   // LDS slab rows: row s <-> w = w0-9+s
#define CROWS 48  // c-state rows (== REGC)

// FC1 K-split (r12-proven: 256 slices of 1280, 1024 threads)
#define KSLICE 1280
#define KPHASE 640
#define NSPLIT 256

typedef _Float16 half8 __attribute__((ext_vector_type(8)));
typedef float floatx4 __attribute__((ext_vector_type(4)));

__device__ __forceinline__ float sigm(float x) {
    return 1.0f / (1.0f + __expf(-x));
}
__device__ __forceinline__ float tanh_fast(float x) {
    return 1.0f - 2.0f / (__expf(2.0f * x) + 1.0f);
}

// ---------------- prep kernels (once per launch) ----------------

// wt0[kw][co][cip=96]: cip 0..63 = h ch (orig ci 3+cip), 64..66 = x ch, 67..95 = 0.
__global__ __launch_bounds__(256) void prep_w0(
    const float* __restrict__ cw0, _Float16* __restrict__ wt0)
{
    int e = blockIdx.x * 256 + threadIdx.x;   // < 256*96
    if (e >= 256 * 96) return;
    int co = e / 96, cip = e - co * 96;
    int ci = (cip < 64) ? (3 + cip) : (cip < 67 ? cip - 64 : -1);
    float v[3] = {0.f, 0.f, 0.f};
    if (ci >= 0) {
#pragma unroll
        for (int kw = 0; kw < 3; ++kw)
            v[kw] = cw0[(size_t)(co * 67 + ci) * 9 + 3 + kw];
    }
#pragma unroll
    for (int kw = 0; kw < 3; ++kw)
        wt0[(size_t)(kw * 256 + co) * 96 + cip] = (_Float16)v[kw];
}

// wt1[kw][co][ci=128]: direct (z = [h0 64 | h1 64] matches cw1 ci order).
__global__ __launch_bounds__(256) void prep_w1(
    const float* __restrict__ cw1, _Float16* __restrict__ wt1)
{
    int e = blockIdx.x * 256 + threadIdx.x;   // < 256*128
    int co = e >> 7, ci = e & 127;
#pragma unroll
    for (int kw = 0; kw < 3; ++kw)
        wt1[(size_t)(kw * 256 + co) * 128 + ci] =
            (_Float16)cw1[(size_t)(co * 128 + ci) * 9 + 3 + kw];
}

// xT[t][b][w][8] fp16: ch 0..2 from x[b][t][ch][w], 3..7 = 0.
__global__ __launch_bounds__(256) void prep_x(
    const float* __restrict__ x, _Float16* __restrict__ xT)
{
    int e = blockIdx.x * 256 + threadIdx.x;   // < 20*32*256
    if (e >= TSTEPS * BATCH * WIDTH) return;
    int t = e / (BATCH * WIDTH);
    int rem = e - t * BATCH * WIDTH;
    int b = rem >> 8, w = rem & 255;
    half8 v = {};
#pragma unroll
    for (int ci = 0; ci < 3; ++ci)
        v[ci] = (_Float16)x[(size_t)((b * TSTEPS + t) * IN_DIM + ci) * WIDTH + w];
    *(half8*)&xT[(size_t)e * 8] = v;
}

// ---------------- time-chunked ConvLSTM kernel (nst steps/launch) --------
// Structure identical to the r11/r12-proven 431.8us version; geometry moved
// to MARG=8/REGC=48 (3 exact j-tiles) and runtime step count nst (7,7,6).
__global__ __launch_bounds__(512) void conv_chunk(
    const _Float16* __restrict__ xT,   // [t][b][w][8]
    const _Float16* __restrict__ wt0,  // [3][256][96]  (reordered slots)
    const _Float16* __restrict__ wt1,  // [3][256][128]
    const float* __restrict__ cb0,
    const float* __restrict__ cb1,
    _Float16* __restrict__ fcin,       // [b][(t*64+hc)*256+w] fp16
    _Float16* __restrict__ h0g,        // [b][w][64] state between chunks
    _Float16* __restrict__ h1g,
    float* __restrict__ c0g,
    float* __restrict__ c1g,
    int t0, int first, int save, int nst)
{
    __shared__ __align__(16) _Float16 h0s[2][ROWS * 64];
    __shared__ __align__(16) _Float16 h1s[2][ROWS * 64];
    __shared__ __align__(16) _Float16 xs[2][ROWS * 8];
    __shared__ float c0s[CROWS * 64];   // idx n*64 + (hc ^ (owner_kg<<4))
    __shared__ float c1s[CROWS * 64];
    __shared__ __align__(16) _Float16 zero16[8];

    const int b    = blockIdx.x;
    const int w0   = blockIdx.y * 32;
    const int tid  = threadIdx.x;
    const int wave = tid >> 6;
    const int ln = tid & 63;
    const int lr = ln & 15;
    const int kg = ln >> 4;

    // ---- zero-init LDS
    {
        _Float16* h0f = &h0s[0][0];
        _Float16* h1f = &h1s[0][0];
        for (int i = tid; i < 2 * ROWS * 64; i += 512) { h0f[i] = (_Float16)0.0f; h1f[i] = (_Float16)0.0f; }
        for (int i = tid; i < CROWS * 64; i += 512) { c0s[i] = 0.0f; c1s[i] = 0.0f; }
        for (int i = tid; i < ROWS * 8; i += 512) xs[1][i] = (_Float16)0.0f;
        if (tid < 8) zero16[tid] = (_Float16)0.0f;
    }
    __syncthreads();

    // ---- stage x(t0) + load chunk-start state
    {
        if (tid < ROWS) {
            int w = w0 - 9 + tid;
            half8 v = {};
            if (w >= 0 && w < WIDTH)
                v = *(const half8*)&xT[((size_t)(t0 * BATCH + b) * WIDTH + w) * 8];
            *(half8*)&xs[0][tid * 8] = v;
        }
        if (!first) {
            for (int i = tid; i < REGC * 8; i += 512) {
                int row = 1 + (i >> 3), c = i & 7;
                int w = w0 - 9 + row;
                half8 v0 = {}, v1 = {};
                if (w >= 0 && w < WIDTH) {
                    v0 = *(const half8*)&h0g[((size_t)b * WIDTH + w) * 64 + c * 8];
                    v1 = *(const half8*)&h1g[((size_t)b * WIDTH + w) * 64 + c * 8];
                }
                int phys = c ^ (row & 7);
                *(half8*)&h0s[1][row * 64 + phys * 8] = v0;
                *(half8*)&h1s[1][row * 64 + phys * 8] = v1;
            }
            for (int i = tid; i < REGC * 64; i += 512) {
                int n = i >> 6, hc = i & 63;
                int w = w0 - 8 + n;
                float v0 = 0.f, v1 = 0.f;
                if (w >= 0 && w < WIDTH) {
                    v0 = c0g[((size_t)b * WIDTH + w) * 64 + hc];
                    v1 = c1g[((size_t)b * WIDTH + w) * 64 + hc];
                }
                int ci = n * 64 + (hc ^ (((n >> 2) & 3) << 4));
                c0s[ci] = v0;
                c1s[ci] = v1;
            }
        }
    }

    if (wave < 4) {
        // ================= LAYER-0 WAVES =================
        const int hc = wave * 16 + lr;

        half8 b0r[3][3][4];
#pragma unroll
        for (int kw = 0; kw < 3; ++kw)
#pragma unroll
        for (int kf = 0; kf < 3; ++kf)
#pragma unroll
        for (int cf = 0; cf < 4; ++cf)
            b0r[kw][kf][cf] = *(const half8*)&wt0[
                (size_t)(kw * 256 + cf * 64 + hc) * 96 + kf * 32 + kg * 8];

        float cbr0[4];
#pragma unroll
        for (int cf = 0; cf < 4; ++cf) cbr0[cf] = cb0[cf * 64 + hc];

        __syncthreads();   // init barrier

        for (int p = 0; p <= nst; ++p) {
            const int rd = (p ^ 1) & 1;
            const int wr = p & 1;
            half8 xreg = {};
            const bool xst = (p < nst - 1) && (tid < ROWS);
            if (xst) {
                int w = w0 - 9 + tid;
                if (w >= 0 && w < WIDTH)
                    xreg = *(const half8*)&xT[((size_t)((t0 + p + 1) * BATCH + b) * WIDTH + w) * 8];
            }
            if (p < nst) {
#pragma unroll
                for (int j = 0; j < 3; ++j) {
                    floatx4 acc[4];
#pragma unroll
                    for (int cf = 0; cf < 4; ++cf) acc[cf] = (floatx4)0.0f;
                    __builtin_amdgcn_s_setprio(1);
#pragma unroll
                    for (int kw = 0; kw < 3; ++kw)
#pragma unroll
                    for (int kf = 0; kf < 3; ++kf) {
                        int row = 16 * j + lr + kw;     // <= 49
                        half8 a;
                        if (kf < 2) {
                            int phys = (kf * 4 + kg) ^ (row & 7);
                            a = *(const half8*)&h0s[rd][row * 64 + phys * 8];
                        } else {
                            a = (kg == 0) ? *(const half8*)&xs[wr][row * 8]
                                          : *(const half8*)&zero16[0];
                        }
#pragma unroll
                        for (int cf = 0; cf < 4; ++cf)
                            acc[cf] = __builtin_amdgcn_mfma_f32_16x16x32_f16(a, b0r[kw][kf][cf], acc[cf], 0, 0, 0);
                    }
                    __builtin_amdgcn_s_setprio(0);
#pragma unroll
                    for (int r = 0; r < 4; ++r) {
                        int n = 16 * j + kg * 4 + r;    // 0..47, all real cols
                        int cidx = n * 64 + (hc ^ (kg << 4));
                        float cv = c0s[cidx];
                        float cn = sigm(acc[1][r] + cbr0[1]) * cv
                                 + sigm(acc[0][r] + cbr0[0]) * tanh_fast(acc[3][r] + cbr0[3]);
                        c0s[cidx] = cn;
                        int w = w0 - 8 + n;
                        if (w >= 0 && w < WIDTH) {   // domain zero-pad preserved
                            _Float16 hv = (_Float16)(sigm(acc[2][r] + cbr0[2]) * tanh_fast(cn));
                            int rowo = n + 1;        // 1..48 < ROWS
                            int phys = (hc >> 3) ^ (rowo & 7);
                            *((_Float16*)((char*)&h0s[wr][0] + rowo * 128 + phys * 16 + (hc & 7) * 2)) = hv;
                        }
                    }
                }
            }
            if (xst) *(half8*)&xs[(p + 1) & 1][tid * 8] = xreg;
            __syncthreads();
        }
    } else {
        // ================= LAYER-1 WAVES =================
        const int hc = (wave - 4) * 16 + lr;

        half8 b1r[3][4][4];
#pragma unroll
        for (int kw = 0; kw < 3; ++kw)
#pragma unroll
        for (int kf = 0; kf < 4; ++kf)
#pragma unroll
        for (int cf = 0; cf < 4; ++cf)
            b1r[kw][kf][cf] = *(const half8*)&wt1[
                (size_t)(kw * 256 + cf * 64 + hc) * 128 + kf * 32 + kg * 8];

        float cbr1[4];
#pragma unroll
        for (int cf = 0; cf < 4; ++cf) cbr1[cf] = cb1[cf * 64 + hc];

        __syncthreads();   // init barrier

        for (int p = 0; p <= nst; ++p) {
            const int rd   = (p ^ 1) & 1;
            const int h1rd = p & 1;
            if (p >= 1) {
#pragma unroll
                for (int j = 0; j < 3; ++j) {
                    floatx4 acc[4];
#pragma unroll
                    for (int cf = 0; cf < 4; ++cf) acc[cf] = (floatx4)0.0f;
                    __builtin_amdgcn_s_setprio(1);
#pragma unroll
                    for (int kw = 0; kw < 3; ++kw)
#pragma unroll
                    for (int kf = 0; kf < 4; ++kf) {
                        int row = 16 * j + lr + kw;
                        half8 a;
                        if (kf < 2) {
                            int phys = (kf * 4 + kg) ^ (row & 7);
                            a = *(const half8*)&h0s[rd][row * 64 + phys * 8];
                        } else {
                            int phys = ((kf - 2) * 4 + kg) ^ (row & 7);
                            a = *(const half8*)&h1s[h1rd][row * 64 + phys * 8];
                        }
#pragma unroll
                        for (int cf = 0; cf < 4; ++cf)
                            acc[cf] = __builtin_amdgcn_mfma_f32_16x16x32_f16(a, b1r[kw][kf][cf], acc[cf], 0, 0, 0);
                    }
                    __builtin_amdgcn_s_setprio(0);
#pragma unroll
                    for (int r = 0; r < 4; ++r) {
                        int n = 16 * j + kg * 4 + r;
                        int cidx = n * 64 + (hc ^ (kg << 4));
                        float cv = c1s[cidx];
                        float cn = sigm(acc[1][r] + cbr1[1]) * cv
                                 + sigm(acc[0][r] + cbr1[0]) * tanh_fast(acc[3][r] + cbr1[3]);
                        c1s[cidx] = cn;
                        _Float16 hv = (_Float16)(sigm(acc[2][r] + cbr1[2]) * tanh_fast(cn));
                        int w = w0 - 8 + n;
                        if (w >= 0 && w < WIDTH) {
                            int rowo = n + 1;
                            int phys = (hc >> 3) ^ (rowo & 7);
                            *((_Float16*)((char*)&h1s[rd][0] + rowo * 128 + phys * 16 + (hc & 7) * 2)) = hv;
                        }
                        if (n >= CORE && n < CORE + 32)   // core: w in [w0, w0+32)
                            fcin[(size_t)b * FC1_IN + (size_t)((t0 + p - 1) * HID + hc) * WIDTH + w] = hv;
                    }
                }
            }
            __syncthreads();
        }
    }

    // ---- store core state for next chunk (h0/h1 final in buffer 0)
    if (save) {
        for (int i = tid; i < 32 * 64; i += 512) {
            int n = CORE + (i >> 6);
            int hc = i & 63;
            int w = w0 + (i >> 6);
            int rowo = n + 1;
            int physh = (hc >> 3) ^ (rowo & 7);
            h0g[((size_t)b * WIDTH + w) * 64 + hc] = h0s[0][rowo * 64 + physh * 8 + (hc & 7)];
            h1g[((size_t)b * WIDTH + w) * 64 + hc] = h1s[0][rowo * 64 + physh * 8 + (hc & 7)];
            int ci = n * 64 + (hc ^ (((n >> 2) & 3) << 4));
            c0g[((size_t)b * WIDTH + w) * 64 + hc] = c0s[ci];
            c1g[((size_t)b * WIDTH + w) * 64 + hc] = c1s[ci];
        }
    }
}

// ---------------- FC1 fp16 MFMA GEMM, K-split, 16 waves (r12-best) --------
__global__ __launch_bounds__(1024) void fc1_mfma(
    const _Float16* __restrict__ a,   // fcin [32][327680] fp16
    const float* __restrict__ w,      // fc1_w [512][327680] fp32
    float* __restrict__ part)         // [256][512][32] fp32 partials
{
    __shared__ _Float16 alds[32 * 648];

    const int blk = blockIdx.x;
    const int tid = threadIdx.x;
    const int wv  = tid >> 6;         // 0..15, each owns 32 n
    const int ln  = tid & 63;
    const int lg  = ln >> 4;
    const int lr  = ln & 15;
    const int k0  = blk * KSLICE;

    floatx4 acc[2][2];
#pragma unroll
    for (int bt = 0; bt < 2; ++bt)
#pragma unroll
        for (int nt = 0; nt < 2; ++nt) acc[bt][nt] = (floatx4)0.0f;

    const float* wbase[2];
#pragma unroll
    for (int nt = 0; nt < 2; ++nt)
        wbase[nt] = w + (size_t)(wv * 32 + nt * 16 + lr) * FC1_IN + k0 + lg * 8;

    for (int p = 0; p < 2; ++p) {
        __syncthreads();
        for (int i = tid; i < 32 * 80; i += 1024) {
            int r = i / 80;
            int c = (i - r * 80) * 8;
            *(half8*)&alds[r * 648 + c] =
                *(const half8*)&a[(size_t)r * FC1_IN + k0 + p * KPHASE + c];
        }
        __syncthreads();

        for (int kc = 0; kc < KPHASE / 32; ++kc) {
            half8 af0 = *(const half8*)&alds[lr * 648 + kc * 32 + lg * 8];
            half8 af1 = *(const half8*)&alds[(16 + lr) * 648 + kc * 32 + lg * 8];
#pragma unroll
            for (int nt = 0; nt < 2; ++nt) {
                const float* wp = wbase[nt] + p * KPHASE + kc * 32;
                float4 wlo = *(const float4*)wp;
                float4 whi = *(const float4*)(wp + 4);
                half8 bf;
                bf[0] = (_Float16)wlo.x; bf[1] = (_Float16)wlo.y;
                bf[2] = (_Float16)wlo.z; bf[3] = (_Float16)wlo.w;
                bf[4] = (_Float16)whi.x; bf[5] = (_Float16)whi.y;
                bf[6] = (_Float16)whi.z; bf[7] = (_Float16)whi.w;
                acc[0][nt] = __builtin_amdgcn_mfma_f32_16x16x32_f16(af0, bf, acc[0][nt], 0, 0, 0);
                acc[1][nt] = __builtin_amdgcn_mfma_f32_16x16x32_f16(af1, bf, acc[1][nt], 0, 0, 0);
            }
        }
    }

#pragma unroll
    for (int bt = 0; bt < 2; ++bt)
#pragma unroll
        for (int nt = 0; nt < 2; ++nt) {
            int n = wv * 32 + nt * 16 + lr;
            int b = bt * 16 + lg * 4;
            *(float4*)&part[((size_t)blk * FC1_OUT + n) * BATCH + b] =
                *(float4*)&acc[bt][nt];
        }
}

__global__ __launch_bounds__(256) void fc1_reduce(
    const float* __restrict__ part, const float* __restrict__ b1,
    float* __restrict__ z1)
{
    int e = blockIdx.x * 256 + threadIdx.x;  // e = n*32 + b
    float s = 0.0f;
    for (int ks = 0; ks < NSPLIT; ++ks)
        s += part[(size_t)ks * (FC1_OUT * BATCH) + e];
    int n = e >> 5, b = e & 31;
    float v = s + b1[n];
    z1[(size_t)b * FC1_OUT + n] = v > 0.0f ? v : 0.0f;
}

__global__ __launch_bounds__(128) void fc2_kernel(
    const float* __restrict__ z1, const float* __restrict__ w2,
    const float* __restrict__ b2, float* __restrict__ out)
{
    int t = threadIdx.x;
    if (t >= BATCH * OUT_DIM) return;
    int b = t / OUT_DIM, n = t - b * OUT_DIM;
    const float* zr = z1 + (size_t)b * FC1_OUT;
    const float* wr = w2 + (size_t)n * FC1_OUT;
    float acc = b2[n];
    for (int k = 0; k < FC1_OUT; ++k) acc += zr[k] * wr[k];
    if (n == 2) acc = sigm(acc);
    out[(size_t)b * OUT_DIM + n] = acc;
}

extern "C" void kernel_launch(void* const* d_in, const int* in_sizes, int n_in,
                              void* d_out, int out_size, void* d_ws, size_t ws_size,
                              hipStream_t stream) {
    const float* x   = (const float*)d_in[0];
    const float* cw0 = (const float*)d_in[1];
    const float* cb0 = (const float*)d_in[2];
    const float* cw1 = (const float*)d_in[3];
    const float* cb1 = (const float*)d_in[4];
    const float* w1  = (const float*)d_in[5];
    const float* b1  = (const float*)d_in[6];
    const float* w2  = (const float*)d_in[7];
    const float* b2  = (const float*)d_in[8];
    float* out = (float*)d_out;

    const size_t S = (size_t)BATCH * WIDTH * HID;   // 524288 elements
    char* p = (char*)d_ws;
    auto alloc = [&](size_t bytes) { char* r = p; p += (bytes + 255) & ~(size_t)255; return r; };

    _Float16* wt0  = (_Float16*)alloc((size_t)3 * 256 * 96 * 2);
    _Float16* wt1  = (_Float16*)alloc((size_t)3 * 256 * 128 * 2);
    _Float16* xT   = (_Float16*)alloc((size_t)TSTEPS * BATCH * WIDTH * 8 * 2);
    _Float16* fcin = (_Float16*)alloc((size_t)BATCH * FC1_IN * 2);
    _Float16* h0g  = (_Float16*)alloc(S * 2);
    _Float16* h1g  = (_Float16*)alloc(S * 2);
    float*    c0g  = (float*)alloc(S * 4);
    float*    c1g  = (float*)alloc(S * 4);
    float*    part = (float*)alloc((size_t)NSPLIT * FC1_OUT * BATCH * 4);
    float*    z1   = (float*)alloc((size_t)BATCH * FC1_OUT * 4);

    prep_w0<<<96, 256, 0, stream>>>(cw0, wt0);
    prep_w1<<<128, 256, 0, stream>>>(cw1, wt1);
    prep_x<<<(TSTEPS * BATCH * WIDTH + 255) / 256, 256, 0, stream>>>(x, xT);

    const int t0s[3]  = {0, 7, 14};
    const int nsts[3] = {7, 7, 6};
    for (int k = 0; k < 3; ++k) {
        conv_chunk<<<dim3(BATCH, 8), 512, 0, stream>>>(
            xT, wt0, wt1, cb0, cb1, fcin, h0g, h1g, c0g, c1g,
            t0s[k], (k == 0) ? 1 : 0, (k < 2) ? 1 : 0, nsts[k]);
    }

    fc1_mfma<<<NSPLIT, 1024, 0, stream>>>(fcin, w1, part);
    fc1_reduce<<<64, 256, 0, stream>>>(part, b1, z1);
    fc2_kernel<<<1, 128, 0, stream>>>(z1, w2, b2, out);
}

// Round 19
// 394.730 us; speedup vs baseline: 1.9718x; 1.0099x over previous
//
#include <hip/hip_runtime.h>
#include <hip/hip_bf16.h>
#include <cstddef>

// Problem constants
#define BATCH 32
#define TSTEPS 20
#define IN_DIM 3
#define WIDTH 256
#define HID 64
#define FC1_IN 327680   // HID * TSTEPS * WIDTH
#define FC1_OUT 512
#define OUT_DIM 3

// Conv time-chunking geometry: 3 chunks of (7,7,6) steps. (r18-proven)
#define MARG 8
#define REGC 48
#define CORE 8
#define ROWS 50
#define CROWS 48

// FC1: 256 K-slices of 1280; B row-contiguous loads staged through LDS
// (reg-pipelined chunks of K=64), A staged once. 148KB LDS, 1 block/CU.
#define KSLICE 1280
#define NSPLIT 256
#define ALDS_STR 1288   // halfs per A row: 2576B = 644 words == 4 mod 32 banks

typedef _Float16 half8 __attribute__((ext_vector_type(8)));
typedef _Float16 half4 __attribute__((ext_vector_type(4)));
typedef float floatx4 __attribute__((ext_vector_type(4)));

__device__ __forceinline__ float sigm(float x) {
    return 1.0f / (1.0f + __expf(-x));
}
__device__ __forceinline__ float tanh_fast(float x) {
    return 1.0f - 2.0f / (__expf(2.0f * x) + 1.0f);
}

// ---------------- prep kernels (once per launch) ----------------

// wt0[kw][co][cip=96]: cip 0..63 = h ch (orig ci 3+cip), 64..66 = x ch, 67..95 = 0.
__global__ __launch_bounds__(256) void prep_w0(
    const float* __restrict__ cw0, _Float16* __restrict__ wt0)
{
    int e = blockIdx.x * 256 + threadIdx.x;   // < 256*96
    if (e >= 256 * 96) return;
    int co = e / 96, cip = e - co * 96;
    int ci = (cip < 64) ? (3 + cip) : (cip < 67 ? cip - 64 : -1);
    float v[3] = {0.f, 0.f, 0.f};
    if (ci >= 0) {
#pragma unroll
        for (int kw = 0; kw < 3; ++kw)
            v[kw] = cw0[(size_t)(co * 67 + ci) * 9 + 3 + kw];
    }
#pragma unroll
    for (int kw = 0; kw < 3; ++kw)
        wt0[(size_t)(kw * 256 + co) * 96 + cip] = (_Float16)v[kw];
}

// wt1[kw][co][ci=128]: direct (z = [h0 64 | h1 64] matches cw1 ci order).
__global__ __launch_bounds__(256) void prep_w1(
    const float* __restrict__ cw1, _Float16* __restrict__ wt1)
{
    int e = blockIdx.x * 256 + threadIdx.x;   // < 256*128
    int co = e >> 7, ci = e & 127;
#pragma unroll
    for (int kw = 0; kw < 3; ++kw)
        wt1[(size_t)(kw * 256 + co) * 128 + ci] =
            (_Float16)cw1[(size_t)(co * 128 + ci) * 9 + 3 + kw];
}

// xT[t][b][w][8] fp16: ch 0..2 from x[b][t][ch][w], 3..7 = 0.
__global__ __launch_bounds__(256) void prep_x(
    const float* __restrict__ x, _Float16* __restrict__ xT)
{
    int e = blockIdx.x * 256 + threadIdx.x;   // < 20*32*256
    if (e >= TSTEPS * BATCH * WIDTH) return;
    int t = e / (BATCH * WIDTH);
    int rem = e - t * BATCH * WIDTH;
    int b = rem >> 8, w = rem & 255;
    half8 v = {};
#pragma unroll
    for (int ci = 0; ci < 3; ++ci)
        v[ci] = (_Float16)x[(size_t)((b * TSTEPS + t) * IN_DIM + ci) * WIDTH + w];
    *(half8*)&xT[(size_t)e * 8] = v;
}

// ---------------- time-chunked ConvLSTM kernel (nst steps/launch) --------
// Identical to r18 (398.6us-proven).
__global__ __launch_bounds__(512) void conv_chunk(
    const _Float16* __restrict__ xT,   // [t][b][w][8]
    const _Float16* __restrict__ wt0,  // [3][256][96]  (reordered slots)
    const _Float16* __restrict__ wt1,  // [3][256][128]
    const float* __restrict__ cb0,
    const float* __restrict__ cb1,
    _Float16* __restrict__ fcin,       // [b][(t*64+hc)*256+w] fp16
    _Float16* __restrict__ h0g,        // [b][w][64] state between chunks
    _Float16* __restrict__ h1g,
    float* __restrict__ c0g,
    float* __restrict__ c1g,
    int t0, int first, int save, int nst)
{
    __shared__ __align__(16) _Float16 h0s[2][ROWS * 64];
    __shared__ __align__(16) _Float16 h1s[2][ROWS * 64];
    __shared__ __align__(16) _Float16 xs[2][ROWS * 8];
    __shared__ float c0s[CROWS * 64];   // idx n*64 + (hc ^ (owner_kg<<4))
    __shared__ float c1s[CROWS * 64];
    __shared__ __align__(16) _Float16 zero16[8];

    const int b    = blockIdx.x;
    const int w0   = blockIdx.y * 32;
    const int tid  = threadIdx.x;
    const int wave = tid >> 6;
    const int ln = tid & 63;
    const int lr = ln & 15;
    const int kg = ln >> 4;

    // ---- zero-init LDS
    {
        _Float16* h0f = &h0s[0][0];
        _Float16* h1f = &h1s[0][0];
        for (int i = tid; i < 2 * ROWS * 64; i += 512) { h0f[i] = (_Float16)0.0f; h1f[i] = (_Float16)0.0f; }
        for (int i = tid; i < CROWS * 64; i += 512) { c0s[i] = 0.0f; c1s[i] = 0.0f; }
        for (int i = tid; i < ROWS * 8; i += 512) xs[1][i] = (_Float16)0.0f;
        if (tid < 8) zero16[tid] = (_Float16)0.0f;
    }
    __syncthreads();

    // ---- stage x(t0) + load chunk-start state
    {
        if (tid < ROWS) {
            int w = w0 - 9 + tid;
            half8 v = {};
            if (w >= 0 && w < WIDTH)
                v = *(const half8*)&xT[((size_t)(t0 * BATCH + b) * WIDTH + w) * 8];
            *(half8*)&xs[0][tid * 8] = v;
        }
        if (!first) {
            for (int i = tid; i < REGC * 8; i += 512) {
                int row = 1 + (i >> 3), c = i & 7;
                int w = w0 - 9 + row;
                half8 v0 = {}, v1 = {};
                if (w >= 0 && w < WIDTH) {
                    v0 = *(const half8*)&h0g[((size_t)b * WIDTH + w) * 64 + c * 8];
                    v1 = *(const half8*)&h1g[((size_t)b * WIDTH + w) * 64 + c * 8];
                }
                int phys = c ^ (row & 7);
                *(half8*)&h0s[1][row * 64 + phys * 8] = v0;
                *(half8*)&h1s[1][row * 64 + phys * 8] = v1;
            }
            for (int i = tid; i < REGC * 64; i += 512) {
                int n = i >> 6, hc = i & 63;
                int w = w0 - 8 + n;
                float v0 = 0.f, v1 = 0.f;
                if (w >= 0 && w < WIDTH) {
                    v0 = c0g[((size_t)b * WIDTH + w) * 64 + hc];
                    v1 = c1g[((size_t)b * WIDTH + w) * 64 + hc];
                }
                int ci = n * 64 + (hc ^ (((n >> 2) & 3) << 4));
                c0s[ci] = v0;
                c1s[ci] = v1;
            }
        }
    }

    if (wave < 4) {
        // ================= LAYER-0 WAVES =================
        const int hc = wave * 16 + lr;

        half8 b0r[3][3][4];
#pragma unroll
        for (int kw = 0; kw < 3; ++kw)
#pragma unroll
        for (int kf = 0; kf < 3; ++kf)
#pragma unroll
        for (int cf = 0; cf < 4; ++cf)
            b0r[kw][kf][cf] = *(const half8*)&wt0[
                (size_t)(kw * 256 + cf * 64 + hc) * 96 + kf * 32 + kg * 8];

        float cbr0[4];
#pragma unroll
        for (int cf = 0; cf < 4; ++cf) cbr0[cf] = cb0[cf * 64 + hc];

        __syncthreads();   // init barrier

        for (int p = 0; p <= nst; ++p) {
            const int rd = (p ^ 1) & 1;
            const int wr = p & 1;
            half8 xreg = {};
            const bool xst = (p < nst - 1) && (tid < ROWS);
            if (xst) {
                int w = w0 - 9 + tid;
                if (w >= 0 && w < WIDTH)
                    xreg = *(const half8*)&xT[((size_t)((t0 + p + 1) * BATCH + b) * WIDTH + w) * 8];
            }
            if (p < nst) {
#pragma unroll
                for (int j = 0; j < 3; ++j) {
                    floatx4 acc[4];
#pragma unroll
                    for (int cf = 0; cf < 4; ++cf) acc[cf] = (floatx4)0.0f;
                    __builtin_amdgcn_s_setprio(1);
#pragma unroll
                    for (int kw = 0; kw < 3; ++kw)
#pragma unroll
                    for (int kf = 0; kf < 3; ++kf) {
                        int row = 16 * j + lr + kw;     // <= 49
                        half8 a;
                        if (kf < 2) {
                            int phys = (kf * 4 + kg) ^ (row & 7);
                            a = *(const half8*)&h0s[rd][row * 64 + phys * 8];
                        } else {
                            a = (kg == 0) ? *(const half8*)&xs[wr][row * 8]
                                          : *(const half8*)&zero16[0];
                        }
#pragma unroll
                        for (int cf = 0; cf < 4; ++cf)
                            acc[cf] = __builtin_amdgcn_mfma_f32_16x16x32_f16(a, b0r[kw][kf][cf], acc[cf], 0, 0, 0);
                    }
                    __builtin_amdgcn_s_setprio(0);
#pragma unroll
                    for (int r = 0; r < 4; ++r) {
                        int n = 16 * j + kg * 4 + r;    // 0..47, all real cols
                        int cidx = n * 64 + (hc ^ (kg << 4));
                        float cv = c0s[cidx];
                        float cn = sigm(acc[1][r] + cbr0[1]) * cv
                                 + sigm(acc[0][r] + cbr0[0]) * tanh_fast(acc[3][r] + cbr0[3]);
                        c0s[cidx] = cn;
                        int w = w0 - 8 + n;
                        if (w >= 0 && w < WIDTH) {   // domain zero-pad preserved
                            _Float16 hv = (_Float16)(sigm(acc[2][r] + cbr0[2]) * tanh_fast(cn));
                            int rowo = n + 1;        // 1..48 < ROWS
                            int phys = (hc >> 3) ^ (rowo & 7);
                            *((_Float16*)((char*)&h0s[wr][0] + rowo * 128 + phys * 16 + (hc & 7) * 2)) = hv;
                        }
                    }
                }
            }
            if (xst) *(half8*)&xs[(p + 1) & 1][tid * 8] = xreg;
            __syncthreads();
        }
    } else {
        // ================= LAYER-1 WAVES =================
        const int hc = (wave - 4) * 16 + lr;

        half8 b1r[3][4][4];
#pragma unroll
        for (int kw = 0; kw < 3; ++kw)
#pragma unroll
        for (int kf = 0; kf < 4; ++kf)
#pragma unroll
        for (int cf = 0; cf < 4; ++cf)
            b1r[kw][kf][cf] = *(const half8*)&wt1[
                (size_t)(kw * 256 + cf * 64 + hc) * 128 + kf * 32 + kg * 8];

        float cbr1[4];
#pragma unroll
        for (int cf = 0; cf < 4; ++cf) cbr1[cf] = cb1[cf * 64 + hc];

        __syncthreads();   // init barrier

        for (int p = 0; p <= nst; ++p) {
            const int rd   = (p ^ 1) & 1;
            const int h1rd = p & 1;
            if (p >= 1) {
#pragma unroll
                for (int j = 0; j < 3; ++j) {
                    floatx4 acc[4];
#pragma unroll
                    for (int cf = 0; cf < 4; ++cf) acc[cf] = (floatx4)0.0f;
                    __builtin_amdgcn_s_setprio(1);
#pragma unroll
                    for (int kw = 0; kw < 3; ++kw)
#pragma unroll
                    for (int kf = 0; kf < 4; ++kf) {
                        int row = 16 * j + lr + kw;
                        half8 a;
                        if (kf < 2) {
                            int phys = (kf * 4 + kg) ^ (row & 7);
                            a = *(const half8*)&h0s[rd][row * 64 + phys * 8];
                        } else {
                            int phys = ((kf - 2) * 4 + kg) ^ (row & 7);
                            a = *(const half8*)&h1s[h1rd][row * 64 + phys * 8];
                        }
#pragma unroll
                        for (int cf = 0; cf < 4; ++cf)
                            acc[cf] = __builtin_amdgcn_mfma_f32_16x16x32_f16(a, b1r[kw][kf][cf], acc[cf], 0, 0, 0);
                    }
                    __builtin_amdgcn_s_setprio(0);
#pragma unroll
                    for (int r = 0; r < 4; ++r) {
                        int n = 16 * j + kg * 4 + r;
                        int cidx = n * 64 + (hc ^ (kg << 4));
                        float cv = c1s[cidx];
                        float cn = sigm(acc[1][r] + cbr1[1]) * cv
                                 + sigm(acc[0][r] + cbr1[0]) * tanh_fast(acc[3][r] + cbr1[3]);
                        c1s[cidx] = cn;
                        _Float16 hv = (_Float16)(sigm(acc[2][r] + cbr1[2]) * tanh_fast(cn));
                        int w = w0 - 8 + n;
                        if (w >= 0 && w < WIDTH) {
                            int rowo = n + 1;
                            int phys = (hc >> 3) ^ (rowo & 7);
                            *((_Float16*)((char*)&h1s[rd][0] + rowo * 128 + phys * 16 + (hc & 7) * 2)) = hv;
                        }
                        if (n >= CORE && n < CORE + 32)   // core: w in [w0, w0+32)
                            fcin[(size_t)b * FC1_IN + (size_t)((t0 + p - 1) * HID + hc) * WIDTH + w] = hv;
                    }
                }
            }
            __syncthreads();
        }
    }

    // ---- store core state for next chunk (h0/h1 final in buffer 0)
    if (save) {
        for (int i = tid; i < 32 * 64; i += 512) {
            int n = CORE + (i >> 6);
            int hc = i & 63;
            int w = w0 + (i >> 6);
            int rowo = n + 1;
            int physh = (hc >> 3) ^ (rowo & 7);
            h0g[((size_t)b * WIDTH + w) * 64 + hc] = h0s[0][rowo * 64 + physh * 8 + (hc & 7)];
            h1g[((size_t)b * WIDTH + w) * 64 + hc] = h1s[0][rowo * 64 + physh * 8 + (hc & 7)];
            int ci = n * 64 + (hc ^ (((n >> 2) & 3) << 4));
            c0g[((size_t)b * WIDTH + w) * 64 + hc] = c0s[ci];
            c1g[((size_t)b * WIDTH + w) * 64 + hc] = c1s[ci];
        }
    }
}

// ---------------- FC1 fp16 MFMA GEMM: row-contiguous B via LDS -----------
// 256 blocks (K-slice 1280), 512 threads = 8 waves. A staged once (82KB).
// B processed in 20 chunks of K=64: regs hold chunk cc+1 (16 float4/lane,
// row-contiguous 256B runs) while MFMA consumes LDS chunk cc (64KB, swizzled).
// Avoids the 16-row x 64B strided gather (rows are 5*2^18 B apart -> same
// HBM channel bits) that capped the old version at ~3.3 TB/s.
__global__ __launch_bounds__(512) void fc1_mfma(
    const _Float16* __restrict__ a,   // fcin [32][327680] fp16
    const float* __restrict__ w,      // fc1_w [512][327680] fp32
    float* __restrict__ part)         // [256][512][32] fp32 partials
{
    __shared__ _Float16 alds[32 * ALDS_STR];            // 82,432 B
    __shared__ __align__(16) _Float16 blds[512 * 64];   // 65,536 B

    const int blk = blockIdx.x;
    const int tid = threadIdx.x;
    const int wv  = tid >> 6;
    const int ln  = tid & 63;
    const int lg  = ln >> 4;      // k-group for MFMA fragments
    const int lr  = ln & 15;
    const int k0  = blk * KSLICE;

    // stage A: 32 rows x 1280 halfs (once)
    for (int i = tid; i < 32 * 160; i += 512) {
        int r = i / 160;
        int c = (i - r * 160) * 8;
        *(half8*)&alds[r * ALDS_STR + c] =
            *(const half8*)&a[(size_t)r * FC1_IN + k0 + c];
    }

    const float4* w4 = (const float4*)w;
    const int lrow = ln >> 4;     // 0..3: row-in-quad for loads
    const int lcol = ln & 15;     // 16B column within 64-float chunk

    // load chunk 0 into regs (rows wv*64..+63, K [k0, k0+64))
    float4 rr[16];
#pragma unroll
    for (int i = 0; i < 16; ++i) {
        int row = wv * 64 + i * 4 + lrow;
        rr[i] = w4[(size_t)row * (FC1_IN / 4) + (size_t)(k0 >> 2) + lcol];
    }

    floatx4 acc[2][4];
#pragma unroll
    for (int bt = 0; bt < 2; ++bt)
#pragma unroll
        for (int nt = 0; nt < 4; ++nt) acc[bt][nt] = (floatx4)0.0f;

    for (int cc = 0; cc < 20; ++cc) {
        __syncthreads();   // prev MFMA done with blds; A staged (first iter)
        // convert + write chunk cc to LDS (swizzled 16B chunks within 128B rows)
#pragma unroll
        for (int i = 0; i < 16; ++i) {
            int row = wv * 64 + i * 4 + lrow;
            int c = lcol >> 1, h = lcol & 1;
            int phys = c ^ (row & 7);
            half4 hv;
            hv[0] = (_Float16)rr[i].x; hv[1] = (_Float16)rr[i].y;
            hv[2] = (_Float16)rr[i].z; hv[3] = (_Float16)rr[i].w;
            *(half4*)((char*)blds + row * 128 + phys * 16 + h * 8) = hv;
        }
        // issue loads for chunk cc+1 (in flight across the MFMA section)
        if (cc < 19) {
#pragma unroll
            for (int i = 0; i < 16; ++i) {
                int row = wv * 64 + i * 4 + lrow;
                rr[i] = w4[(size_t)row * (FC1_IN / 4)
                           + (size_t)((k0 + (cc + 1) * 64) >> 2) + lcol];
            }
        }
        __syncthreads();   // blds chunk cc visible
#pragma unroll
        for (int kc2 = 0; kc2 < 2; ++kc2) {
            int kk = cc * 64 + kc2 * 32 + lg * 8;
            half8 af0 = *(const half8*)&alds[lr * ALDS_STR + kk];
            half8 af1 = *(const half8*)&alds[(16 + lr) * ALDS_STR + kk];
#pragma unroll
            for (int nt = 0; nt < 4; ++nt) {
                int row = wv * 64 + nt * 16 + lr;
                int phys = (kc2 * 4 + lg) ^ (row & 7);
                half8 bf = *(const half8*)((const char*)blds + row * 128 + phys * 16);
                acc[0][nt] = __builtin_amdgcn_mfma_f32_16x16x32_f16(af0, bf, acc[0][nt], 0, 0, 0);
                acc[1][nt] = __builtin_amdgcn_mfma_f32_16x16x32_f16(af1, bf, acc[1][nt], 0, 0, 0);
            }
        }
    }

#pragma unroll
    for (int bt = 0; bt < 2; ++bt)
#pragma unroll
        for (int nt = 0; nt < 4; ++nt) {
            int n = wv * 64 + nt * 16 + lr;
            int b = bt * 16 + lg * 4;
            *(float4*)&part[((size_t)blk * FC1_OUT + n) * BATCH + b] =
                *(float4*)&acc[bt][nt];
        }
}

__global__ __launch_bounds__(256) void fc1_reduce(
    const float* __restrict__ part, const float* __restrict__ b1,
    float* __restrict__ z1)
{
    int e = blockIdx.x * 256 + threadIdx.x;  // e = n*32 + b
    float s = 0.0f;
    for (int ks = 0; ks < NSPLIT; ++ks)
        s += part[(size_t)ks * (FC1_OUT * BATCH) + e];
    int n = e >> 5, b = e & 31;
    float v = s + b1[n];
    z1[(size_t)b * FC1_OUT + n] = v > 0.0f ? v : 0.0f;
}

__global__ __launch_bounds__(128) void fc2_kernel(
    const float* __restrict__ z1, const float* __restrict__ w2,
    const float* __restrict__ b2, float* __restrict__ out)
{
    int t = threadIdx.x;
    if (t >= BATCH * OUT_DIM) return;
    int b = t / OUT_DIM, n = t - b * OUT_DIM;
    const float* zr = z1 + (size_t)b * FC1_OUT;
    const float* wr = w2 + (size_t)n * FC1_OUT;
    float acc = b2[n];
    for (int k = 0; k < FC1_OUT; ++k) acc += zr[k] * wr[k];
    if (n == 2) acc = sigm(acc);
    out[(size_t)b * OUT_DIM + n] = acc;
}

extern "C" void kernel_launch(void* const* d_in, const int* in_sizes, int n_in,
                              void* d_out, int out_size, void* d_ws, size_t ws_size,
                              hipStream_t stream) {
    const float* x   = (const float*)d_in[0];
    const float* cw0 = (const float*)d_in[1];
    const float* cb0 = (const float*)d_in[2];
    const float* cw1 = (const float*)d_in[3];
    const float* cb1 = (const float*)d_in[4];
    const float* w1  = (const float*)d_in[5];
    const float* b1  = (const float*)d_in[6];
    const float* w2  = (const float*)d_in[7];
    const float* b2  = (const float*)d_in[8];
    float* out = (float*)d_out;

    const size_t S = (size_t)BATCH * WIDTH * HID;   // 524288 elements
    char* p = (char*)d_ws;
    auto alloc = [&](size_t bytes) { char* r = p; p += (bytes + 255) & ~(size_t)255; return r; };

    _Float16* wt0  = (_Float16*)alloc((size_t)3 * 256 * 96 * 2);
    _Float16* wt1  = (_Float16*)alloc((size_t)3 * 256 * 128 * 2);
    _Float16* xT   = (_Float16*)alloc((size_t)TSTEPS * BATCH * WIDTH * 8 * 2);
    _Float16* fcin = (_Float16*)alloc((size_t)BATCH * FC1_IN * 2);
    _Float16* h0g  = (_Float16*)alloc(S * 2);
    _Float16* h1g  = (_Float16*)alloc(S * 2);
    float*    c0g  = (float*)alloc(S * 4);
    float*    c1g  = (float*)alloc(S * 4);
    float*    part = (float*)alloc((size_t)NSPLIT * FC1_OUT * BATCH * 4);
    float*    z1   = (float*)alloc((size_t)BATCH * FC1_OUT * 4);

    prep_w0<<<96, 256, 0, stream>>>(cw0, wt0);
    prep_w1<<<128, 256, 0, stream>>>(cw1, wt1);
    prep_x<<<(TSTEPS * BATCH * WIDTH + 255) / 256, 256, 0, stream>>>(x, xT);

    const int t0s[3]  = {0, 7, 14};
    const int nsts[3] = {7, 7, 6};
    for (int k = 0; k < 3; ++k) {
        conv_chunk<<<dim3(BATCH, 8), 512, 0, stream>>>(
            xT, wt0, wt1, cb0, cb1, fcin, h0g, h1g, c0g, c1g,
            t0s[k], (k == 0) ? 1 : 0, (k < 2) ? 1 : 0, nsts[k]);
    }

    fc1_mfma<<<NSPLIT, 512, 0, stream>>>(fcin, w1, part);
    fc1_reduce<<<64, 256, 0, stream>>>(part, b1, z1);
    fc2_kernel<<<1, 128, 0, stream>>>(z1, w2, b2, out);
}

// Round 20
// 365.145 us; speedup vs baseline: 2.1315x; 1.0810x over previous
//
#include <hip/hip_runtime.h>
#include <hip/hip_bf16.h>
#include <cstddef>

// Problem constants
#define BATCH 32
#define TSTEPS 20
#define IN_DIM 3
#define WIDTH 256
#define HID 64
#define FC1_IN 327680   // HID * TSTEPS * WIDTH
#define FC1_OUT 512
#define OUT_DIM 3

// Conv time-chunking geometry: 3 chunks of (7,7,6) steps. (r18-proven)
#define MARG 8
#define REGC 48
#define CORE 8
#define ROWS 50
#define CROWS 48

// FC1: r19 row-contiguous-B version (best measured)
#define KSLICE 1280
#define NSPLIT 256
#define ALDS_STR 1288

typedef _Float16 half8 __attribute__((ext_vector_type(8)));
typedef _Float16 half4 __attribute__((ext_vector_type(4)));
typedef float floatx4 __attribute__((ext_vector_type(4)));

__device__ __forceinline__ float sigm(float x) {
    return 1.0f / (1.0f + __expf(-x));
}
__device__ __forceinline__ float tanh_fast(float x) {
    return 1.0f - 2.0f / (__expf(2.0f * x) + 1.0f);
}

// ---------------- prep kernels (once per launch) ----------------

// wt0[kw][co][cip=96]: cip 0..63 = h ch (orig ci 3+cip), 64..66 = x ch, 67..95 = 0.
__global__ __launch_bounds__(256) void prep_w0(
    const float* __restrict__ cw0, _Float16* __restrict__ wt0)
{
    int e = blockIdx.x * 256 + threadIdx.x;   // < 256*96
    if (e >= 256 * 96) return;
    int co = e / 96, cip = e - co * 96;
    int ci = (cip < 64) ? (3 + cip) : (cip < 67 ? cip - 64 : -1);
    float v[3] = {0.f, 0.f, 0.f};
    if (ci >= 0) {
#pragma unroll
        for (int kw = 0; kw < 3; ++kw)
            v[kw] = cw0[(size_t)(co * 67 + ci) * 9 + 3 + kw];
    }
#pragma unroll
    for (int kw = 0; kw < 3; ++kw)
        wt0[(size_t)(kw * 256 + co) * 96 + cip] = (_Float16)v[kw];
}

// wt1[kw][co][ci=128]: direct (z = [h0 64 | h1 64] matches cw1 ci order).
__global__ __launch_bounds__(256) void prep_w1(
    const float* __restrict__ cw1, _Float16* __restrict__ wt1)
{
    int e = blockIdx.x * 256 + threadIdx.x;   // < 256*128
    int co = e >> 7, ci = e & 127;
#pragma unroll
    for (int kw = 0; kw < 3; ++kw)
        wt1[(size_t)(kw * 256 + co) * 128 + ci] =
            (_Float16)cw1[(size_t)(co * 128 + ci) * 9 + 3 + kw];
}

// xT[t][b][w][8] fp16: ch 0..2 from x[b][t][ch][w], 3..7 = 0.
__global__ __launch_bounds__(256) void prep_x(
    const float* __restrict__ x, _Float16* __restrict__ xT)
{
    int e = blockIdx.x * 256 + threadIdx.x;   // < 20*32*256
    if (e >= TSTEPS * BATCH * WIDTH) return;
    int t = e / (BATCH * WIDTH);
    int rem = e - t * BATCH * WIDTH;
    int b = rem >> 8, w = rem & 255;
    half8 v = {};
#pragma unroll
    for (int ci = 0; ci < 3; ++ci)
        v[ci] = (_Float16)x[(size_t)((b * TSTEPS + t) * IN_DIM + ci) * WIDTH + w];
    *(half8*)&xT[(size_t)e * 8] = v;
}

// ---------------- time-chunked ConvLSTM kernel (nst steps/launch) --------
// r18 structure; polish: fcin written as half4 (4 consecutive w per (j,kg),
// core-aligned since CORE%4==0) instead of 12 scattered 2B stores/thread/
// phase; chunk-save batched to half8/float4 (c-swizzle is bits 4-5 only ->
// 8-wide hc groups stay contiguous).
__global__ __launch_bounds__(512) void conv_chunk(
    const _Float16* __restrict__ xT,   // [t][b][w][8]
    const _Float16* __restrict__ wt0,  // [3][256][96]  (reordered slots)
    const _Float16* __restrict__ wt1,  // [3][256][128]
    const float* __restrict__ cb0,
    const float* __restrict__ cb1,
    _Float16* __restrict__ fcin,       // [b][(t*64+hc)*256+w] fp16
    _Float16* __restrict__ h0g,        // [b][w][64] state between chunks
    _Float16* __restrict__ h1g,
    float* __restrict__ c0g,
    float* __restrict__ c1g,
    int t0, int first, int save, int nst)
{
    __shared__ __align__(16) _Float16 h0s[2][ROWS * 64];
    __shared__ __align__(16) _Float16 h1s[2][ROWS * 64];
    __shared__ __align__(16) _Float16 xs[2][ROWS * 8];
    __shared__ float c0s[CROWS * 64];   // idx n*64 + (hc ^ (owner_kg<<4))
    __shared__ float c1s[CROWS * 64];
    __shared__ __align__(16) _Float16 zero16[8];

    const int b    = blockIdx.x;
    const int w0   = blockIdx.y * 32;
    const int tid  = threadIdx.x;
    const int wave = tid >> 6;
    const int ln = tid & 63;
    const int lr = ln & 15;
    const int kg = ln >> 4;

    // ---- zero-init LDS
    {
        _Float16* h0f = &h0s[0][0];
        _Float16* h1f = &h1s[0][0];
        for (int i = tid; i < 2 * ROWS * 64; i += 512) { h0f[i] = (_Float16)0.0f; h1f[i] = (_Float16)0.0f; }
        for (int i = tid; i < CROWS * 64; i += 512) { c0s[i] = 0.0f; c1s[i] = 0.0f; }
        for (int i = tid; i < ROWS * 8; i += 512) xs[1][i] = (_Float16)0.0f;
        if (tid < 8) zero16[tid] = (_Float16)0.0f;
    }
    __syncthreads();

    // ---- stage x(t0) + load chunk-start state
    {
        if (tid < ROWS) {
            int w = w0 - 9 + tid;
            half8 v = {};
            if (w >= 0 && w < WIDTH)
                v = *(const half8*)&xT[((size_t)(t0 * BATCH + b) * WIDTH + w) * 8];
            *(half8*)&xs[0][tid * 8] = v;
        }
        if (!first) {
            for (int i = tid; i < REGC * 8; i += 512) {
                int row = 1 + (i >> 3), c = i & 7;
                int w = w0 - 9 + row;
                half8 v0 = {}, v1 = {};
                if (w >= 0 && w < WIDTH) {
                    v0 = *(const half8*)&h0g[((size_t)b * WIDTH + w) * 64 + c * 8];
                    v1 = *(const half8*)&h1g[((size_t)b * WIDTH + w) * 64 + c * 8];
                }
                int phys = c ^ (row & 7);
                *(half8*)&h0s[1][row * 64 + phys * 8] = v0;
                *(half8*)&h1s[1][row * 64 + phys * 8] = v1;
            }
            for (int i = tid; i < REGC * 64; i += 512) {
                int n = i >> 6, hc = i & 63;
                int w = w0 - 8 + n;
                float v0 = 0.f, v1 = 0.f;
                if (w >= 0 && w < WIDTH) {
                    v0 = c0g[((size_t)b * WIDTH + w) * 64 + hc];
                    v1 = c1g[((size_t)b * WIDTH + w) * 64 + hc];
                }
                int ci = n * 64 + (hc ^ (((n >> 2) & 3) << 4));
                c0s[ci] = v0;
                c1s[ci] = v1;
            }
        }
    }

    if (wave < 4) {
        // ================= LAYER-0 WAVES =================
        const int hc = wave * 16 + lr;

        half8 b0r[3][3][4];
#pragma unroll
        for (int kw = 0; kw < 3; ++kw)
#pragma unroll
        for (int kf = 0; kf < 3; ++kf)
#pragma unroll
        for (int cf = 0; cf < 4; ++cf)
            b0r[kw][kf][cf] = *(const half8*)&wt0[
                (size_t)(kw * 256 + cf * 64 + hc) * 96 + kf * 32 + kg * 8];

        float cbr0[4];
#pragma unroll
        for (int cf = 0; cf < 4; ++cf) cbr0[cf] = cb0[cf * 64 + hc];

        __syncthreads();   // init barrier

        for (int p = 0; p <= nst; ++p) {
            const int rd = (p ^ 1) & 1;
            const int wr = p & 1;
            half8 xreg = {};
            const bool xst = (p < nst - 1) && (tid < ROWS);
            if (xst) {
                int w = w0 - 9 + tid;
                if (w >= 0 && w < WIDTH)
                    xreg = *(const half8*)&xT[((size_t)((t0 + p + 1) * BATCH + b) * WIDTH + w) * 8];
            }
            if (p < nst) {
#pragma unroll
                for (int j = 0; j < 3; ++j) {
                    floatx4 acc[4];
#pragma unroll
                    for (int cf = 0; cf < 4; ++cf) acc[cf] = (floatx4)0.0f;
                    __builtin_amdgcn_s_setprio(1);
#pragma unroll
                    for (int kw = 0; kw < 3; ++kw)
#pragma unroll
                    for (int kf = 0; kf < 3; ++kf) {
                        int row = 16 * j + lr + kw;     // <= 49
                        half8 a;
                        if (kf < 2) {
                            int phys = (kf * 4 + kg) ^ (row & 7);
                            a = *(const half8*)&h0s[rd][row * 64 + phys * 8];
                        } else {
                            a = (kg == 0) ? *(const half8*)&xs[wr][row * 8]
                                          : *(const half8*)&zero16[0];
                        }
#pragma unroll
                        for (int cf = 0; cf < 4; ++cf)
                            acc[cf] = __builtin_amdgcn_mfma_f32_16x16x32_f16(a, b0r[kw][kf][cf], acc[cf], 0, 0, 0);
                    }
                    __builtin_amdgcn_s_setprio(0);
#pragma unroll
                    for (int r = 0; r < 4; ++r) {
                        int n = 16 * j + kg * 4 + r;    // 0..47, all real cols
                        int cidx = n * 64 + (hc ^ (kg << 4));
                        float cv = c0s[cidx];
                        float cn = sigm(acc[1][r] + cbr0[1]) * cv
                                 + sigm(acc[0][r] + cbr0[0]) * tanh_fast(acc[3][r] + cbr0[3]);
                        c0s[cidx] = cn;
                        int w = w0 - 8 + n;
                        if (w >= 0 && w < WIDTH) {   // domain zero-pad preserved
                            _Float16 hv = (_Float16)(sigm(acc[2][r] + cbr0[2]) * tanh_fast(cn));
                            int rowo = n + 1;        // 1..48 < ROWS
                            int phys = (hc >> 3) ^ (rowo & 7);
                            *((_Float16*)((char*)&h0s[wr][0] + rowo * 128 + phys * 16 + (hc & 7) * 2)) = hv;
                        }
                    }
                }
            }
            if (xst) *(half8*)&xs[(p + 1) & 1][tid * 8] = xreg;
            __syncthreads();
        }
    } else {
        // ================= LAYER-1 WAVES =================
        const int hc = (wave - 4) * 16 + lr;

        half8 b1r[3][4][4];
#pragma unroll
        for (int kw = 0; kw < 3; ++kw)
#pragma unroll
        for (int kf = 0; kf < 4; ++kf)
#pragma unroll
        for (int cf = 0; cf < 4; ++cf)
            b1r[kw][kf][cf] = *(const half8*)&wt1[
                (size_t)(kw * 256 + cf * 64 + hc) * 128 + kf * 32 + kg * 8];

        float cbr1[4];
#pragma unroll
        for (int cf = 0; cf < 4; ++cf) cbr1[cf] = cb1[cf * 64 + hc];

        __syncthreads();   // init barrier

        for (int p = 0; p <= nst; ++p) {
            const int rd   = (p ^ 1) & 1;
            const int h1rd = p & 1;
            if (p >= 1) {
#pragma unroll
                for (int j = 0; j < 3; ++j) {
                    floatx4 acc[4];
#pragma unroll
                    for (int cf = 0; cf < 4; ++cf) acc[cf] = (floatx4)0.0f;
                    __builtin_amdgcn_s_setprio(1);
#pragma unroll
                    for (int kw = 0; kw < 3; ++kw)
#pragma unroll
                    for (int kf = 0; kf < 4; ++kf) {
                        int row = 16 * j + lr + kw;
                        half8 a;
                        if (kf < 2) {
                            int phys = (kf * 4 + kg) ^ (row & 7);
                            a = *(const half8*)&h0s[rd][row * 64 + phys * 8];
                        } else {
                            int phys = ((kf - 2) * 4 + kg) ^ (row & 7);
                            a = *(const half8*)&h1s[h1rd][row * 64 + phys * 8];
                        }
#pragma unroll
                        for (int cf = 0; cf < 4; ++cf)
                            acc[cf] = __builtin_amdgcn_mfma_f32_16x16x32_f16(a, b1r[kw][kf][cf], acc[cf], 0, 0, 0);
                    }
                    __builtin_amdgcn_s_setprio(0);
                    half4 fbuf;
#pragma unroll
                    for (int r = 0; r < 4; ++r) {
                        int n = 16 * j + kg * 4 + r;
                        int cidx = n * 64 + (hc ^ (kg << 4));
                        float cv = c1s[cidx];
                        float cn = sigm(acc[1][r] + cbr1[1]) * cv
                                 + sigm(acc[0][r] + cbr1[0]) * tanh_fast(acc[3][r] + cbr1[3]);
                        c1s[cidx] = cn;
                        _Float16 hv = (_Float16)(sigm(acc[2][r] + cbr1[2]) * tanh_fast(cn));
                        fbuf[r] = hv;
                        int w = w0 - 8 + n;
                        if (w >= 0 && w < WIDTH) {
                            int rowo = n + 1;
                            int phys = (hc >> 3) ^ (rowo & 7);
                            *((_Float16*)((char*)&h1s[rd][0] + rowo * 128 + phys * 16 + (hc & 7) * 2)) = hv;
                        }
                    }
                    int n0 = 16 * j + kg * 4;   // 4-aligned; core block all-in/all-out
                    if (n0 >= CORE && n0 < CORE + 32) {
                        *(half4*)&fcin[(size_t)b * FC1_IN
                                       + (size_t)((t0 + p - 1) * HID + hc) * WIDTH
                                       + (w0 - 8 + n0)] = fbuf;
                    }
                }
            }
            __syncthreads();
        }
    }

    // ---- store core state for next chunk (h0/h1 final in buffer 0), batched
    if (save) {
        for (int i = tid; i < 32 * 8; i += 512) {
            int dn  = i >> 3;          // 0..31
            int hcg = (i & 7) * 8;     // hc group of 8
            int n = CORE + dn;
            int w = w0 + dn;
            int rowo = n + 1;
            half8 v0, v1;
#pragma unroll
            for (int q = 0; q < 8; ++q) {
                int hc = hcg + q;
                int physh = (hc >> 3) ^ (rowo & 7);
                v0[q] = h0s[0][rowo * 64 + physh * 8 + (hc & 7)];
                v1[q] = h1s[0][rowo * 64 + physh * 8 + (hc & 7)];
            }
            size_t gbase = ((size_t)b * WIDTH + w) * 64 + hcg;
            *(half8*)&h0g[gbase] = v0;
            *(half8*)&h1g[gbase] = v1;
            int K = ((n >> 2) & 3) << 4;              // swizzle bits 4-5 only
            int cbase = n * 64 + (hcg ^ K);           // contiguous over q
            *(float4*)&c0g[gbase] = *(float4*)&c0s[cbase];
            *(float4*)&c0g[gbase + 4] = *(float4*)&c0s[cbase + 4];
            *(float4*)&c1g[gbase] = *(float4*)&c1s[cbase];
            *(float4*)&c1g[gbase + 4] = *(float4*)&c1s[cbase + 4];
        }
    }
}

// ---------------- FC1 fp16 MFMA GEMM: row-contiguous B via LDS (r19) -----
__global__ __launch_bounds__(512) void fc1_mfma(
    const _Float16* __restrict__ a,   // fcin [32][327680] fp16
    const float* __restrict__ w,      // fc1_w [512][327680] fp32
    float* __restrict__ part)         // [256][512][32] fp32 partials
{
    __shared__ _Float16 alds[32 * ALDS_STR];            // 82,432 B
    __shared__ __align__(16) _Float16 blds[512 * 64];   // 65,536 B

    const int blk = blockIdx.x;
    const int tid = threadIdx.x;
    const int wv  = tid >> 6;
    const int ln  = tid & 63;
    const int lg  = ln >> 4;
    const int lr  = ln & 15;
    const int k0  = blk * KSLICE;

    for (int i = tid; i < 32 * 160; i += 512) {
        int r = i / 160;
        int c = (i - r * 160) * 8;
        *(half8*)&alds[r * ALDS_STR + c] =
            *(const half8*)&a[(size_t)r * FC1_IN + k0 + c];
    }

    const float4* w4 = (const float4*)w;
    const int lrow = ln >> 4;
    const int lcol = ln & 15;

    float4 rr[16];
#pragma unroll
    for (int i = 0; i < 16; ++i) {
        int row = wv * 64 + i * 4 + lrow;
        rr[i] = w4[(size_t)row * (FC1_IN / 4) + (size_t)(k0 >> 2) + lcol];
    }

    floatx4 acc[2][4];
#pragma unroll
    for (int bt = 0; bt < 2; ++bt)
#pragma unroll
        for (int nt = 0; nt < 4; ++nt) acc[bt][nt] = (floatx4)0.0f;

    for (int cc = 0; cc < 20; ++cc) {
        __syncthreads();
#pragma unroll
        for (int i = 0; i < 16; ++i) {
            int row = wv * 64 + i * 4 + lrow;
            int c = lcol >> 1, h = lcol & 1;
            int phys = c ^ (row & 7);
            half4 hv;
            hv[0] = (_Float16)rr[i].x; hv[1] = (_Float16)rr[i].y;
            hv[2] = (_Float16)rr[i].z; hv[3] = (_Float16)rr[i].w;
            *(half4*)((char*)blds + row * 128 + phys * 16 + h * 8) = hv;
        }
        if (cc < 19) {
#pragma unroll
            for (int i = 0; i < 16; ++i) {
                int row = wv * 64 + i * 4 + lrow;
                rr[i] = w4[(size_t)row * (FC1_IN / 4)
                           + (size_t)((k0 + (cc + 1) * 64) >> 2) + lcol];
            }
        }
        __syncthreads();
#pragma unroll
        for (int kc2 = 0; kc2 < 2; ++kc2) {
            int kk = cc * 64 + kc2 * 32 + lg * 8;
            half8 af0 = *(const half8*)&alds[lr * ALDS_STR + kk];
            half8 af1 = *(const half8*)&alds[(16 + lr) * ALDS_STR + kk];
#pragma unroll
            for (int nt = 0; nt < 4; ++nt) {
                int row = wv * 64 + nt * 16 + lr;
                int phys = (kc2 * 4 + lg) ^ (row & 7);
                half8 bf = *(const half8*)((const char*)blds + row * 128 + phys * 16);
                acc[0][nt] = __builtin_amdgcn_mfma_f32_16x16x32_f16(af0, bf, acc[0][nt], 0, 0, 0);
                acc[1][nt] = __builtin_amdgcn_mfma_f32_16x16x32_f16(af1, bf, acc[1][nt], 0, 0, 0);
            }
        }
    }

#pragma unroll
    for (int bt = 0; bt < 2; ++bt)
#pragma unroll
        for (int nt = 0; nt < 4; ++nt) {
            int n = wv * 64 + nt * 16 + lr;
            int b = bt * 16 + lg * 4;
            *(float4*)&part[((size_t)blk * FC1_OUT + n) * BATCH + b] =
                *(float4*)&acc[bt][nt];
        }
}

__global__ __launch_bounds__(256) void fc1_reduce(
    const float* __restrict__ part, const float* __restrict__ b1,
    float* __restrict__ z1)
{
    int e = blockIdx.x * 256 + threadIdx.x;  // e = n*32 + b
    float s = 0.0f;
    for (int ks = 0; ks < NSPLIT; ++ks)
        s += part[(size_t)ks * (FC1_OUT * BATCH) + e];
    int n = e >> 5, b = e & 31;
    float v = s + b1[n];
    z1[(size_t)b * FC1_OUT + n] = v > 0.0f ? v : 0.0f;
}

__global__ __launch_bounds__(128) void fc2_kernel(
    const float* __restrict__ z1, const float* __restrict__ w2,
    const float* __restrict__ b2, float* __restrict__ out)
{
    int t = threadIdx.x;
    if (t >= BATCH * OUT_DIM) return;
    int b = t / OUT_DIM, n = t - b * OUT_DIM;
    const float* zr = z1 + (size_t)b * FC1_OUT;
    const float* wr = w2 + (size_t)n * FC1_OUT;
    float acc = b2[n];
    for (int k = 0; k < FC1_OUT; ++k) acc += zr[k] * wr[k];
    if (n == 2) acc = sigm(acc);
    out[(size_t)b * OUT_DIM + n] = acc;
}

extern "C" void kernel_launch(void* const* d_in, const int* in_sizes, int n_in,
                              void* d_out, int out_size, void* d_ws, size_t ws_size,
                              hipStream_t stream) {
    const float* x   = (const float*)d_in[0];
    const float* cw0 = (const float*)d_in[1];
    const float* cb0 = (const float*)d_in[2];
    const float* cw1 = (const float*)d_in[3];
    const float* cb1 = (const float*)d_in[4];
    const float* w1  = (const float*)d_in[5];
    const float* b1  = (const float*)d_in[6];
    const float* w2  = (const float*)d_in[7];
    const float* b2  = (const float*)d_in[8];
    float* out = (float*)d_out;

    const size_t S = (size_t)BATCH * WIDTH * HID;   // 524288 elements
    char* p = (char*)d_ws;
    auto alloc = [&](size_t bytes) { char* r = p; p += (bytes + 255) & ~(size_t)255; return r; };

    _Float16* wt0  = (_Float16*)alloc((size_t)3 * 256 * 96 * 2);
    _Float16* wt1  = (_Float16*)alloc((size_t)3 * 256 * 128 * 2);
    _Float16* xT   = (_Float16*)alloc((size_t)TSTEPS * BATCH * WIDTH * 8 * 2);
    _Float16* fcin = (_Float16*)alloc((size_t)BATCH * FC1_IN * 2);
    _Float16* h0g  = (_Float16*)alloc(S * 2);
    _Float16* h1g  = (_Float16*)alloc(S * 2);
    float*    c0g  = (float*)alloc(S * 4);
    float*    c1g  = (float*)alloc(S * 4);
    float*    part = (float*)alloc((size_t)NSPLIT * FC1_OUT * BATCH * 4);
    float*    z1   = (float*)alloc((size_t)BATCH * FC1_OUT * 4);

    prep_w0<<<96, 256, 0, stream>>>(cw0, wt0);
    prep_w1<<<128, 256, 0, stream>>>(cw1, wt1);
    prep_x<<<(TSTEPS * BATCH * WIDTH + 255) / 256, 256, 0, stream>>>(x, xT);

    const int t0s[3]  = {0, 7, 14};
    const int nsts[3] = {7, 7, 6};
    for (int k = 0; k < 3; ++k) {
        conv_chunk<<<dim3(BATCH, 8), 512, 0, stream>>>(
            xT, wt0, wt1, cb0, cb1, fcin, h0g, h1g, c0g, c1g,
            t0s[k], (k == 0) ? 1 : 0, (k < 2) ? 1 : 0, nsts[k]);
    }

    fc1_mfma<<<NSPLIT, 512, 0, stream>>>(fcin, w1, part);
    fc1_reduce<<<64, 256, 0, stream>>>(part, b1, z1);
    fc2_kernel<<<1, 128, 0, stream>>>(z1, w2, b2, out);
}